// Round 12
// baseline (77.438 us; speedup 1.0000x reference)
//
#include <hip/hip_runtime.h>

#define BB 32
#define MM 512
#define SS 10
#define VV 32000
#define DD 128
#define HOPS 3
#define BM (BB * MM)
#define NCHUNK 32          // chunks per b -> grid 32*32 = 1024 blocks for K1/K2
#define CHM (MM / NCHUNK)  // 16 m per chunk -> 4 m per wave
#define PSTRIDE 132        // partial row: 128 num + 1 den + pad

// ====================== PRIMARY PATH (3 kernels, pure f32) ======================

__device__ __forceinline__ void write_partial(const int b, const int c,
                                              const int w, const int lane,
                                              float nx, float ny, float den,
                                              float* __restrict__ pout,
                                              float (*sx)[64], float (*sy)[64],
                                              float* sd) {
    sx[w][lane] = nx; sy[w][lane] = ny;
    if (lane == 0) sd[w] = den;
    __syncthreads();
    if (w == 0) {
        const float ox = sx[0][lane] + sx[1][lane] + sx[2][lane] + sx[3][lane];
        const float oy = sy[0][lane] + sy[1][lane] + sy[2][lane] + sy[3][lane];
        float* prow = pout + ((size_t)b * NCHUNK + c) * PSTRIDE;
        ((float2*)prow)[lane] = make_float2(ox, oy);
        if (lane == 0) prow[DD] = sd[0] + sd[1] + sd[2] + sd[3];
    }
}

// K1 (hop0): gather C0 -> logit, gather C1 -> E1 + weighted acc -> P0. u = hidden.
__global__ __launch_bounds__(256) void hop0_k(const int* __restrict__ story,
                                              const float* __restrict__ C0,
                                              const float* __restrict__ C1,
                                              const float* __restrict__ hidden,
                                              float* __restrict__ E1,
                                              float* __restrict__ P0) {
    const int b = blockIdx.y, c = blockIdx.x;
    const int tid = threadIdx.x;
    const int w = tid >> 6, lane = tid & 63;
    __shared__ float su[DD];
    __shared__ float sx[4][64], sy[4][64];
    __shared__ float sd[4];

    if (tid < DD) su[tid] = hidden[b * DD + tid];
    __syncthreads();
    const float2 uv = ((const float2*)su)[lane];

    float nx = 0.f, ny = 0.f, den = 0.f;
#pragma unroll
    for (int k = 0; k < CHM / 4; ++k) {
        const int m = c * CHM + k * 4 + w;
        const int bm = b * MM + m;
        int tok[SS];
        const int* st = story + (size_t)bm * SS;
#pragma unroll
        for (int s = 0; s < SS; ++s) tok[s] = st[s];

        float ex = 0.f, ey = 0.f;
#pragma unroll
        for (int s = 0; s < SS; ++s) {
            const float2 v = ((const float2*)(C0 + (size_t)tok[s] * DD))[lane];
            ex += v.x; ey += v.y;
        }
        float l = ex * uv.x + ey * uv.y;
#pragma unroll
        for (int off = 32; off; off >>= 1) l += __shfl_xor(l, off, 64);
        const float e = expf(l);

        float rx = 0.f, ry = 0.f;
#pragma unroll
        for (int s = 0; s < SS; ++s) {
            const float2 v = ((const float2*)(C1 + (size_t)tok[s] * DD))[lane];
            rx += v.x; ry += v.y;
        }
        ((float2*)(E1 + (size_t)bm * DD))[lane] = make_float2(rx, ry);
        nx += e * rx; ny += e * ry; den += e;
    }
    write_partial(b, c, w, lane, nx, ny, den, P0, sx, sy, sd);
}

// K2 (hop1): logit from E1; gather C2 -> E2 + weighted acc -> P1; gather C3 -> E3.
// u1 = hidden + red(P0); c==0 materializes u1.
__global__ __launch_bounds__(256) void hop1_k(const int* __restrict__ story,
                                              const float* __restrict__ C2,
                                              const float* __restrict__ C3,
                                              const float* __restrict__ E1,
                                              const float* __restrict__ hidden,
                                              const float* __restrict__ P0,
                                              float* __restrict__ u1,
                                              float* __restrict__ E2,
                                              float* __restrict__ E3,
                                              float* __restrict__ P1) {
    const int b = blockIdx.y, c = blockIdx.x;
    const int tid = threadIdx.x;
    const int w = tid >> 6, lane = tid & 63;
    __shared__ float su[DD];
    __shared__ float sx[4][64], sy[4][64];
    __shared__ float sd[4];

    if (tid < DD) {
        float num = 0.f, dsum = 0.f;
        for (int cc = 0; cc < NCHUNK; ++cc) {
            const float* p = P0 + ((size_t)b * NCHUNK + cc) * PSTRIDE;
            num += p[tid];
            dsum += p[DD];
        }
        const float v = hidden[b * DD + tid] + num / dsum;
        if (c == 0) u1[b * DD + tid] = v;
        su[tid] = v;
    }
    __syncthreads();
    const float2 uv = ((const float2*)su)[lane];

    float nx = 0.f, ny = 0.f, den = 0.f;
#pragma unroll
    for (int k = 0; k < CHM / 4; ++k) {
        const int m = c * CHM + k * 4 + w;
        const int bm = b * MM + m;
        int tok[SS];
        const int* st = story + (size_t)bm * SS;
#pragma unroll
        for (int s = 0; s < SS; ++s) tok[s] = st[s];

        const float2 ev = ((const float2*)(E1 + (size_t)bm * DD))[lane];
        float l = ev.x * uv.x + ev.y * uv.y;
#pragma unroll
        for (int off = 32; off; off >>= 1) l += __shfl_xor(l, off, 64);
        const float e = expf(l);

        float r2x = 0.f, r2y = 0.f;
#pragma unroll
        for (int s = 0; s < SS; ++s) {
            const float2 v = ((const float2*)(C2 + (size_t)tok[s] * DD))[lane];
            r2x += v.x; r2y += v.y;
        }
        float r3x = 0.f, r3y = 0.f;
#pragma unroll
        for (int s = 0; s < SS; ++s) {
            const float2 v = ((const float2*)(C3 + (size_t)tok[s] * DD))[lane];
            r3x += v.x; r3y += v.y;
        }
        ((float2*)(E2 + (size_t)bm * DD))[lane] = make_float2(r2x, r2y);
        ((float2*)(E3 + (size_t)bm * DD))[lane] = make_float2(r3x, r3y);
        nx += e * r2x; ny += e * r2y; den += e;
    }
    write_partial(b, c, w, lane, nx, ny, den, P1, sx, sy, sd);
}

// K3 (hop2 + final): one block per b, 1024 threads (16 waves). Fully dense.
// u2 = u1 + red(P1); logit[bm] from E2; output from E3; uout = u2 + num/den.
__global__ __launch_bounds__(1024) void hop2_final(const float* __restrict__ E2,
                                                   const float* __restrict__ E3,
                                                   const float* __restrict__ u1,
                                                   const float* __restrict__ P1,
                                                   float* __restrict__ logit,
                                                   float* __restrict__ uout) {
    const int b = blockIdx.x;
    const int tid = threadIdx.x;
    const int w = tid >> 6, lane = tid & 63;
    __shared__ float su[DD];
    __shared__ float sx[16][64], sy[16][64];
    __shared__ float sd[16];

    if (tid < DD) {
        float num = 0.f, dsum = 0.f;
        for (int cc = 0; cc < NCHUNK; ++cc) {
            const float* p = P1 + ((size_t)b * NCHUNK + cc) * PSTRIDE;
            num += p[tid];
            dsum += p[DD];
        }
        su[tid] = u1[b * DD + tid] + num / dsum;
    }
    __syncthreads();
    const float2 uv = ((const float2*)su)[lane];

    float nx = 0.f, ny = 0.f, den = 0.f;
#pragma unroll 4
    for (int m = w * 32; m < w * 32 + 32; ++m) {
        const int bm = b * MM + m;
        const float2 ev = ((const float2*)(E2 + (size_t)bm * DD))[lane];
        float l = ev.x * uv.x + ev.y * uv.y;
#pragma unroll
        for (int off = 32; off; off >>= 1) l += __shfl_xor(l, off, 64);
        if (lane == 0) logit[bm] = l;
        const float e = expf(l);
        const float2 rv = ((const float2*)(E3 + (size_t)bm * DD))[lane];
        nx += e * rv.x; ny += e * rv.y; den += e;
    }

    sx[w][lane] = nx; sy[w][lane] = ny;
    if (lane == 0) sd[w] = den;
    __syncthreads();
    if (w == 0) {
        float ox = 0.f, oy = 0.f, od = 0.f;
#pragma unroll
        for (int i = 0; i < 16; ++i) { ox += sx[i][lane]; oy += sy[i][lane]; od += sd[i]; }
        const float2 u2 = ((const float2*)su)[lane];
        ((float2*)(uout + b * DD))[lane] = make_float2(u2.x + ox / od, u2.y + oy / od);
    }
}

// ====================== FALLBACK PATH (round-1, known-good) ======================
__global__ __launch_bounds__(256) void init_u(const float* __restrict__ hidden,
                                              float* __restrict__ u) {
    int i = blockIdx.x * 256 + threadIdx.x;
    if (i < BB * DD) u[i] = hidden[i];
}

__global__ __launch_bounds__(256) void logit_kernel(const int* __restrict__ story,
                                                    const float* __restrict__ Ch,
                                                    const float* __restrict__ u,
                                                    float* __restrict__ logit) {
    int wid = (blockIdx.x * 256 + threadIdx.x) >> 6;
    int lane = threadIdx.x & 63;
    if (wid >= BB * MM) return;
    int b = wid >> 9;
    const int* st = story + (size_t)wid * SS;
    int tok[SS];
#pragma unroll
    for (int s = 0; s < SS; ++s) tok[s] = st[s];
    float ax = 0.f, ay = 0.f;
#pragma unroll
    for (int s = 0; s < SS; ++s) {
        const float2 v = ((const float2*)(Ch + (size_t)tok[s] * DD))[lane];
        ax += v.x; ay += v.y;
    }
    const float2 uv = ((const float2*)(u + b * DD))[lane];
    float p = ax * uv.x + ay * uv.y;
#pragma unroll
    for (int off = 32; off; off >>= 1) p += __shfl_down(p, off, 64);
    if (lane == 0) logit[wid] = p;
}

__global__ __launch_bounds__(256) void softmax_kernel(const float* __restrict__ logit,
                                                      float* __restrict__ prob) {
    int b = blockIdx.x;
    int t = threadIdx.x;
    __shared__ float red[8];
    float l0 = logit[b * MM + t];
    float l1 = logit[b * MM + 256 + t];
    float mx = fmaxf(l0, l1);
#pragma unroll
    for (int off = 32; off; off >>= 1) mx = fmaxf(mx, __shfl_xor(mx, off, 64));
    if ((t & 63) == 0) red[t >> 6] = mx;
    __syncthreads();
    mx = fmaxf(fmaxf(red[0], red[1]), fmaxf(red[2], red[3]));
    float e0 = expf(l0 - mx), e1 = expf(l1 - mx);
    float s = e0 + e1;
#pragma unroll
    for (int off = 32; off; off >>= 1) s += __shfl_xor(s, off, 64);
    if ((t & 63) == 0) red[4 + (t >> 6)] = s;
    __syncthreads();
    s = red[4] + red[5] + red[6] + red[7];
    float inv = 1.0f / s;
    prob[b * MM + t] = e0 * inv;
    prob[b * MM + 256 + t] = e1 * inv;
}

__global__ __launch_bounds__(256) void partial_kernel(const int* __restrict__ story,
                                                      const float* __restrict__ Ch1,
                                                      const float* __restrict__ prob,
                                                      float* __restrict__ partial,
                                                      int chunk) {
    int b = blockIdx.y, c = blockIdx.x;
    int w = threadIdx.x >> 6, lane = threadIdx.x & 63;
    int m0 = c * chunk;
    float ax = 0.f, ay = 0.f;
    for (int m = m0 + w; m < m0 + chunk; m += 4) {
        float pw = prob[b * MM + m];
        const int* st = story + (size_t)(b * MM + m) * SS;
        int tok[SS];
#pragma unroll
        for (int s = 0; s < SS; ++s) tok[s] = st[s];
        float sx = 0.f, sy = 0.f;
#pragma unroll
        for (int s = 0; s < SS; ++s) {
            const float2 v = ((const float2*)(Ch1 + (size_t)tok[s] * DD))[lane];
            sx += v.x; sy += v.y;
        }
        ax += pw * sx; ay += pw * sy;
    }
    __shared__ float redx[4][64];
    __shared__ float redy[4][64];
    redx[w][lane] = ax;
    redy[w][lane] = ay;
    __syncthreads();
    if (w == 0) {
        float ox = redx[0][lane] + redx[1][lane] + redx[2][lane] + redx[3][lane];
        float oy = redy[0][lane] + redy[1][lane] + redy[2][lane] + redy[3][lane];
        float2* dst = (float2*)(partial + ((size_t)b * gridDim.x + c) * DD);
        dst[lane] = make_float2(ox, oy);
    }
}

__global__ __launch_bounds__(256) void update_kernel(const float* __restrict__ partial,
                                                     float* __restrict__ u, int NC) {
    int i = blockIdx.x * 256 + threadIdx.x;
    if (i >= BB * DD) return;
    int b = i >> 7, d = i & 127;
    float s = 0.f;
    for (int c = 0; c < NC; ++c) s += partial[((size_t)b * NC + c) * DD + d];
    u[i] += s;
}

extern "C" void kernel_launch(void* const* d_in, const int* in_sizes, int n_in,
                              void* d_out, int out_size, void* d_ws, size_t ws_size,
                              hipStream_t stream) {
    const int*   story  = (const int*)d_in[0];
    const float* hidden = (const float*)d_in[1];
    const float* Cmat   = (const float*)d_in[2];

    float* out   = (float*)d_out;
    float* logit = out;              // final prob_logit [B,M]
    float* uout  = out + BB * MM;    // final u [B,D]

    // ws floats: E1 E2 E3 | P0 P1 | u1
    const size_t szE  = (size_t)BM * DD;
    const size_t szP  = (size_t)BB * NCHUNK * PSTRIDE;
    const size_t need = (3 * szE + 2 * szP + BB * DD) * sizeof(float);

    if (ws_size >= need) {
        float* E1 = (float*)d_ws;
        float* E2 = E1 + szE;
        float* E3 = E2 + szE;
        float* P0 = E3 + szE;
        float* P1 = P0 + szP;
        float* u1 = P1 + szP;

        const float* C0 = Cmat;
        const float* C1 = Cmat + (size_t)1 * VV * DD;
        const float* C2 = Cmat + (size_t)2 * VV * DD;
        const float* C3 = Cmat + (size_t)3 * VV * DD;

        hop0_k<<<dim3(NCHUNK, BB), 256, 0, stream>>>(story, C0, C1, hidden, E1, P0);
        hop1_k<<<dim3(NCHUNK, BB), 256, 0, stream>>>(story, C2, C3, E1, hidden,
                                                     P0, u1, E2, E3, P1);
        hop2_final<<<BB, 1024, 0, stream>>>(E2, E3, u1, P1, logit, uout);
    } else {
        float* prob = (float*)d_ws;
        int NC = 32;
        while (NC > 1 && (size_t)(BB * MM + BB * NC * DD) * 4 > ws_size) NC >>= 1;
        float* partial = prob + BB * MM;
        int chunk = MM / NC;

        init_u<<<(BB * DD + 255) / 256, 256, 0, stream>>>(hidden, uout);
        for (int h = 0; h < HOPS; ++h) {
            const float* Ca = Cmat + (size_t)h * VV * DD;
            const float* Cc = Cmat + (size_t)(h + 1) * VV * DD;
            logit_kernel<<<(BB * MM) / 4, 256, 0, stream>>>(story, Ca, uout, logit);
            softmax_kernel<<<BB, 256, 0, stream>>>(logit, prob);
            partial_kernel<<<dim3(NC, BB), 256, 0, stream>>>(story, Cc, prob, partial, chunk);
            update_kernel<<<(BB * DD + 255) / 256, 256, 0, stream>>>(partial, uout, NC);
        }
    }
}